// Round 4
// baseline (2551.129 us; speedup 1.0000x reference)
//
#include <hip/hip_runtime.h>
#include <math.h>

// Problem constants
#define B_   16
#define T_   64
#define N_   22
#define D_   64
#define K_   4
#define E_   8
#define H_   64
#define TW   59                 // valid time steps (t=2..60 absolute)
#define M_   (B_ * TW)          // 944
#define NE_  (N_ * E_)          // 176
#define MT2  128                // rows per block
#define XTOT (B_ * T_ * N_ * D_)   // 1,441,792

typedef __attribute__((ext_vector_type(8))) short short8;
typedef __attribute__((ext_vector_type(4))) float float4v;

// workspace layout
#define ERRWS_BYTES  ((size_t)(M_ * N_ * E_) * 4)          // 664,576
#define XH_OFF       (ERRWS_BYTES)
#define XIMG_BYTES   ((size_t)XTOT * 2)                    // 2,883,584
#define XL_OFF       (XH_OFF + XIMG_BYTES)

// Round-to-nearest bf16 hi + truncated bf16 of residual. Combined rel err ~2^-16.
__device__ inline void split2(float f, unsigned& hi, unsigned& lo) {
    unsigned u = __float_as_uint(f);
    unsigned r = (u + 0x7fffu + ((u >> 16) & 1u)) & 0xffff0000u;
    hi = r >> 16;
    float rem = f - __uint_as_float(r);
    lo = __float_as_uint(rem) >> 16;
}

// ---------------------------------------------------------------------------
// Precompute: x -> bf16 hi/lo images (same linear layout as x). ~6 MB churn.
__global__ __launch_bounds__(256) void xsplit_kernel(
    const float* __restrict__ x, short* __restrict__ xh, short* __restrict__ xl)
{
    int i = (blockIdx.x * 256 + threadIdx.x) * 4;
    if (i >= XTOT) return;
    float4 v = *(const float4*)(x + i);
    unsigned h0, h1, h2, h3, l0, l1, l2, l3;
    split2(v.x, h0, l0); split2(v.y, h1, l1);
    split2(v.z, h2, l2); split2(v.w, h3, l3);
    uint2 hp, lp;
    hp.x = h0 | (h1 << 16); hp.y = h2 | (h3 << 16);
    lp.x = l0 | (l1 << 16); lp.y = l2 | (l3 << 16);
    *(uint2*)(xh + i) = hp;
    *(uint2*)(xl + i) = lp;
}

// ---------------------------------------------------------------------------
// Main kernel. Block = (n, e, mtile of 128 rows), swizzled so all 8 mtiles of
// one (n,e) share an XCD (blk%8 == e). 4 waves, each 32 rows x 64 cols.
// GEMM1: A double-buffered register prefetch from pre-split xh/xl; W loaded
// fp32 from global one chunk ahead, split in-register, staged to LDS images.
// GEMM2/3: A from pre-split h images in padded LDS; same W path (W2, W3).
__global__ __launch_bounds__(256, 3) void moe_err_kernel(
    const float* __restrict__ x, const short* __restrict__ xh,
    const short* __restrict__ xl, const int* __restrict__ nb,
    const float* __restrict__ W1, const float* __restrict__ W2,
    const float* __restrict__ W3,
    const float* __restrict__ b1, const float* __restrict__ b2,
    const float* __restrict__ b3, float* __restrict__ err_ws)
{
    const int tid = threadIdx.x;
    const int w   = tid >> 6;
    const int L   = tid & 63;
    const int g   = blockIdx.x;
    // swizzle: g = e + 8*mt + 64*n  ->  g%8 == e == XCD for all mtiles of ne
    const int e  = g & 7;
    const int mt = (g >> 3) & 7;
    const int n  = g >> 6;
    const int ne = n * E_ + e;

    __shared__ __align__(16) unsigned char wbuf[16384];   // 16 images x 1KB
    __shared__ __align__(16) short h1h[128][72];          // 18,432 B
    __shared__ __align__(16) short h1l[128][72];          // 18,432 B

    const int lrow    = L & 15;
    const int dseg    = (L >> 4) * 8;
    const int rowbase = mt * MT2 + w * 32;

    // per-rowtile lane row -> base into x images (xl = xh + XTOT)
    const short* xhrow[2];
    #pragma unroll
    for (int rt = 0; rt < 2; ++rt) {
        int m  = rowbase + rt * 16 + lrow;
        int mc = m < M_ ? m : M_ - 1;
        int b = mc / TW, t = mc % TW;
        xhrow[rt] = xh + (size_t)(b * T_ + t) * N_ * D_;
    }

    // neighbor offsets (wave-uniform scalars)
    const int o0 = __builtin_amdgcn_readfirstlane(nb[n * K_ + 0]) * D_;
    const int o1 = __builtin_amdgcn_readfirstlane(nb[n * K_ + 1]) * D_;
    const int o2 = __builtin_amdgcn_readfirstlane(nb[n * K_ + 2]) * D_;
    const int o3 = __builtin_amdgcn_readfirstlane(nb[n * K_ + 3]) * D_;

    const float* W1ne = W1 + (size_t)ne * 1280 * 64;
    const float* W2ne = W2 + (size_t)ne * 4096;
    const float* W3ne = W3 + (size_t)ne * 4096;
    auto csrc = [&](int c) {
        return c < 20 ? W1ne + (size_t)c * 4096 : (c == 20 ? W2ne : W3ne);
    };

    // ---- W pipeline: fp32 prefetch -> in-register split -> LDS image store.
    // Wave w owns image pairs pair0, pair0+1 (pairIdx = s2*4+cf).
    const int pair0 = w * 2;
    float wregf[2][8];
    uint4 wpkh[2], wpkl[2];
    auto loadWf = [&](const float* src) {
        #pragma unroll
        for (int p = 0; p < 2; ++p) {
            int pi  = pair0 + p;
            int k0  = (pi >> 2) * 32 + (L >> 4) * 8;
            int col = (pi & 3) * 16 + (L & 15);
            const float* sp = src + k0 * 64 + col;
            #pragma unroll
            for (int j = 0; j < 8; ++j) wregf[p][j] = sp[j * 64];
        }
    };
    auto packW = [&]() {
        #pragma unroll
        for (int p = 0; p < 2; ++p) {
            unsigned h[8], l[8];
            #pragma unroll
            for (int j = 0; j < 8; ++j) split2(wregf[p][j], h[j], l[j]);
            wpkh[p].x = h[0] | (h[1] << 16); wpkh[p].y = h[2] | (h[3] << 16);
            wpkh[p].z = h[4] | (h[5] << 16); wpkh[p].w = h[6] | (h[7] << 16);
            wpkl[p].x = l[0] | (l[1] << 16); wpkl[p].y = l[2] | (l[3] << 16);
            wpkl[p].z = l[4] | (l[5] << 16); wpkl[p].w = l[6] | (l[7] << 16);
        }
    };
    auto storeW = [&]() {
        #pragma unroll
        for (int p = 0; p < 2; ++p) {
            char* bp = (char*)wbuf + (size_t)(pair0 + p) * 2048 + (size_t)L * 16;
            *(uint4*)bp          = wpkh[p];
            *(uint4*)(bp + 1024) = wpkl[p];
        }
    };
    auto bfrag = [&](int s2, int cf, int hl) -> short8 {
        return *(const short8*)(wbuf + (size_t)((s2 * 4 + cf) * 2 + hl) * 1024
                                     + (size_t)L * 16);
    };

    // ---- A double-buffered register prefetch
    short8 Ah[2][2][2], Al[2][2][2];   // [buf][s2][rt]
    auto loadA = [&](int c, int buf) {
        int dt = c >> 2, kk = c & 3;
        int o  = (kk == 0) ? o0 : (kk == 1) ? o1 : (kk == 2) ? o2 : o3;
        int off = dt * (N_ * D_) + o;
        #pragma unroll
        for (int s2 = 0; s2 < 2; ++s2)
            #pragma unroll
            for (int rt = 0; rt < 2; ++rt) {
                const short* hp = xhrow[rt] + off + s2 * 32 + dseg;
                Ah[buf][s2][rt] = *(const short8*)hp;
                Al[buf][s2][rt] = *(const short8*)(hp + XTOT);
            }
    };

    float4v acc1[2][4];
    #pragma unroll
    for (int rt = 0; rt < 2; ++rt)
        #pragma unroll
        for (int cf = 0; cf < 4; ++cf) acc1[rt][cf] = (float4v)0.f;

    loadWf(csrc(0));
    loadA(0, 0);
    packW();

    // ---------------- GEMM1: 20 chunks of K=64 ----------------
    #pragma unroll 2
    for (int c = 0; c < 20; ++c) {
        const int buf = c & 1;
        __syncthreads();            // prior chunk's B-reads done
        storeW();
        __syncthreads();            // images visible

        if (c < 19) loadA(c + 1, buf ^ 1);
        loadWf(csrc(c + 1));        // c==19 prefetches W2

        #pragma unroll
        for (int s2 = 0; s2 < 2; ++s2)
            #pragma unroll
            for (int cf = 0; cf < 4; ++cf) {
                short8 bh = bfrag(s2, cf, 0);
                short8 bl = bfrag(s2, cf, 1);
                #pragma unroll
                for (int rt = 0; rt < 2; ++rt) {
                    acc1[rt][cf] = __builtin_amdgcn_mfma_f32_16x16x32_bf16(Ah[buf][s2][rt], bh, acc1[rt][cf], 0, 0, 0);
                    acc1[rt][cf] = __builtin_amdgcn_mfma_f32_16x16x32_bf16(Ah[buf][s2][rt], bl, acc1[rt][cf], 0, 0, 0);
                    acc1[rt][cf] = __builtin_amdgcn_mfma_f32_16x16x32_bf16(Al[buf][s2][rt], bh, acc1[rt][cf], 0, 0, 0);
                }
            }
        packW();                    // split next chunk's W (waits its loads)
    }

    // ---------------- h1 = relu(acc1 + b1) -> split bf16 LDS; stage W2 ------
    __syncthreads();                // last chunk's B-reads done
    storeW();                       // W2 images
    const int ccol = L & 15;
    const int qrow = (L >> 4) * 4;
    #pragma unroll
    for (int cf = 0; cf < 4; ++cf) {
        float bv = b1[(size_t)ne * H_ + cf * 16 + ccol];
        #pragma unroll
        for (int rt = 0; rt < 2; ++rt)
            #pragma unroll
            for (int reg = 0; reg < 4; ++reg) {
                int r = w * 32 + rt * 16 + qrow + reg;      // wave-private rows
                float hv = fmaxf(acc1[rt][cf][reg] + bv, 0.f);
                unsigned hi, lo;
                split2(hv, hi, lo);
                h1h[r][cf * 16 + ccol] = (short)hi;
                h1l[r][cf * 16 + ccol] = (short)lo;
            }
    }
    loadWf(csrc(21));               // prefetch W3 behind barrier + GEMM2
    __syncthreads();                // W2 images + h1 visible

    // ---------------- GEMM2: h1 @ W2 (K=64) ----------------
    float4v acc2[2][4];
    #pragma unroll
    for (int rt = 0; rt < 2; ++rt)
        #pragma unroll
        for (int cf = 0; cf < 4; ++cf) acc2[rt][cf] = (float4v)0.f;

    #pragma unroll
    for (int s2 = 0; s2 < 2; ++s2) {
        short8 ah[2], al[2];
        #pragma unroll
        for (int rt = 0; rt < 2; ++rt) {
            ah[rt] = *(const short8*)&h1h[w * 32 + rt * 16 + lrow][s2 * 32 + dseg];
            al[rt] = *(const short8*)&h1l[w * 32 + rt * 16 + lrow][s2 * 32 + dseg];
        }
        #pragma unroll
        for (int cf = 0; cf < 4; ++cf) {
            short8 bh = bfrag(s2, cf, 0);
            short8 bl = bfrag(s2, cf, 1);
            #pragma unroll
            for (int rt = 0; rt < 2; ++rt) {
                acc2[rt][cf] = __builtin_amdgcn_mfma_f32_16x16x32_bf16(ah[rt], bh, acc2[rt][cf], 0, 0, 0);
                acc2[rt][cf] = __builtin_amdgcn_mfma_f32_16x16x32_bf16(ah[rt], bl, acc2[rt][cf], 0, 0, 0);
                acc2[rt][cf] = __builtin_amdgcn_mfma_f32_16x16x32_bf16(al[rt], bh, acc2[rt][cf], 0, 0, 0);
            }
        }
    }
    packW();                        // split W3

    // ---------------- h2 = relu(acc2 + b2) -> split bf16 LDS; stage W3 ------
    __syncthreads();                // all waves done reading W2 images
    storeW();                       // W3 images
    #pragma unroll
    for (int cf = 0; cf < 4; ++cf) {
        float bv = b2[(size_t)ne * H_ + cf * 16 + ccol];
        #pragma unroll
        for (int rt = 0; rt < 2; ++rt)
            #pragma unroll
            for (int reg = 0; reg < 4; ++reg) {
                int r = w * 32 + rt * 16 + qrow + reg;
                float hv = fmaxf(acc2[rt][cf][reg] + bv, 0.f);
                unsigned hi, lo;
                split2(hv, hi, lo);
                h1h[r][cf * 16 + ccol] = (short)hi;
                h1l[r][cf * 16 + ccol] = (short)lo;
            }
    }
    __syncthreads();                // W3 images + h2 visible

    // ---------------- GEMM3: h2 @ W3 -> pred; err epilogue ----------------
    float4v acc3[2][4];
    #pragma unroll
    for (int rt = 0; rt < 2; ++rt)
        #pragma unroll
        for (int cf = 0; cf < 4; ++cf) acc3[rt][cf] = (float4v)0.f;

    #pragma unroll
    for (int s2 = 0; s2 < 2; ++s2) {
        short8 ah[2], al[2];
        #pragma unroll
        for (int rt = 0; rt < 2; ++rt) {
            ah[rt] = *(const short8*)&h1h[w * 32 + rt * 16 + lrow][s2 * 32 + dseg];
            al[rt] = *(const short8*)&h1l[w * 32 + rt * 16 + lrow][s2 * 32 + dseg];
        }
        #pragma unroll
        for (int cf = 0; cf < 4; ++cf) {
            short8 bh = bfrag(s2, cf, 0);
            short8 bl = bfrag(s2, cf, 1);
            #pragma unroll
            for (int rt = 0; rt < 2; ++rt) {
                acc3[rt][cf] = __builtin_amdgcn_mfma_f32_16x16x32_bf16(ah[rt], bh, acc3[rt][cf], 0, 0, 0);
                acc3[rt][cf] = __builtin_amdgcn_mfma_f32_16x16x32_bf16(ah[rt], bl, acc3[rt][cf], 0, 0, 0);
                acc3[rt][cf] = __builtin_amdgcn_mfma_f32_16x16x32_bf16(al[rt], bh, acc3[rt][cf], 0, 0, 0);
            }
        }
    }

    float b3v[4];
    #pragma unroll
    for (int cf = 0; cf < 4; ++cf) b3v[cf] = b3[(size_t)ne * D_ + cf * 16 + ccol];

    #pragma unroll
    for (int rt = 0; rt < 2; ++rt) {
        float s[4] = {0.f, 0.f, 0.f, 0.f};
        #pragma unroll
        for (int reg = 0; reg < 4; ++reg) {
            int m  = rowbase + rt * 16 + qrow + reg;
            int mc = m < M_ ? m : M_ - 1;
            int b = mc / TW, t = mc % TW;
            const float* yp = x + ((size_t)(b * T_ + t + 2) * N_ + n) * D_;
            #pragma unroll
            for (int cf = 0; cf < 4; ++cf) {
                float d = acc3[rt][cf][reg] + b3v[cf] - yp[cf * 16 + ccol];
                s[reg] += d * d;
            }
        }
        #pragma unroll
        for (int reg = 0; reg < 4; ++reg) {
            s[reg] += __shfl_xor(s[reg], 1);
            s[reg] += __shfl_xor(s[reg], 2);
            s[reg] += __shfl_xor(s[reg], 4);
            s[reg] += __shfl_xor(s[reg], 8);
        }
        if (ccol == 0) {
            #pragma unroll
            for (int reg = 0; reg < 4; ++reg) {
                int m = rowbase + rt * 16 + qrow + reg;
                if (m < M_) err_ws[((size_t)m * N_ + n) * E_ + e] = s[reg] * (1.f / 64.f);
            }
        }
    }
}

// ---------------------------------------------------------------------------
// Reduce: per (m,n) min/argmin over E, softmax(-err) KL; block atomicAdd.
__global__ __launch_bounds__(256) void moe_reduce_kernel(
    const float* __restrict__ err_ws, float* __restrict__ out)
{
    const int tid = threadIdx.x;
    const int idx = blockIdx.x * 256 + tid;
    float v = 0.f;
    if (idx < M_ * N_) {
        const int m = idx / N_, n = idx % N_;
        const float* ep = err_ws + (size_t)idx * E_;
        float ev[E_];
        float mn = ep[0];
        int am = 0;
        ev[0] = mn;
        #pragma unroll
        for (int i = 1; i < E_; ++i) {
            ev[i] = ep[i];
            if (ev[i] < mn) { mn = ev[i]; am = i; }
        }
        float p[E_];
        float Z = 0.f;
        #pragma unroll
        for (int i = 0; i < E_; ++i) { p[i] = expf(mn - ev[i]); Z += p[i]; }
        const float invZ = 1.f / Z;
        float kl = 0.f;
        #pragma unroll
        for (int i = 0; i < E_; ++i) {
            float q = p[i] * invZ;
            kl += q * (logf(q + 1e-9f) + 2.0794415416798357f);  // log(8)
        }
        v = mn + 0.01f * kl;
        const int t = m % TW, b = m / TW;
        if (t == TW - 1 && n == N_ - 1) out[1 + b] = (float)am;
    }
    __shared__ float sd[256];
    sd[tid] = v;
    __syncthreads();
    for (int s = 128; s > 0; s >>= 1) {
        if (tid < s) sd[tid] += sd[tid + s];
        __syncthreads();
    }
    if (tid == 0) atomicAdd(out, sd[0] * (1.f / 20160.f));  // / B / (N-1) / (T-4)
}

__global__ void init_out_kernel(float* out)
{
    if (threadIdx.x == 0) out[0] = 0.f;
}

extern "C" void kernel_launch(void* const* d_in, const int* in_sizes, int n_in,
                              void* d_out, int out_size, void* d_ws, size_t ws_size,
                              hipStream_t stream)
{
    const float* x  = (const float*)d_in[0];
    const int*   nb = (const int*)d_in[1];
    const float* W1 = (const float*)d_in[2];
    const float* b1 = (const float*)d_in[3];
    const float* W2 = (const float*)d_in[4];
    const float* b2 = (const float*)d_in[5];
    const float* W3 = (const float*)d_in[6];
    const float* b3 = (const float*)d_in[7];
    float* out    = (float*)d_out;
    float* err_ws = (float*)d_ws;
    short* xh     = (short*)((char*)d_ws + XH_OFF);
    short* xl     = (short*)((char*)d_ws + XL_OFF);

    hipLaunchKernelGGL(init_out_kernel, dim3(1), dim3(64), 0, stream, out);
    hipLaunchKernelGGL(xsplit_kernel, dim3(1408), dim3(256), 0, stream, x, xh, xl);
    hipLaunchKernelGGL(moe_err_kernel, dim3(N_ * E_ * 8), dim3(256), 0, stream,
                       x, xh, xl, nb, W1, W2, W3, b1, b2, b3, err_ws);
    const int nred = (M_ * N_ + 255) / 256;
    hipLaunchKernelGGL(moe_reduce_kernel, dim3(nred), dim3(256), 0, stream, err_ws, out);
}

// Round 5
// 397.550 us; speedup vs baseline: 6.4171x; 6.4171x over previous
//
#include <hip/hip_runtime.h>
#include <math.h>

// Problem constants
#define B_   16
#define T_   64
#define N_   22
#define D_   64
#define K_   4
#define E_   8
#define DT_  5
#define H_   64
#define TW   59                 // valid time steps (t=2..60 absolute)
#define M_   (B_ * TW)          // 944
#define NE_  (N_ * E_)          // 176
#define MT2  128                // rows per block
#define NCHUNK 22               // 20 W1 chunks + W2 + W3
#define CHUNK_BYTES 16384       // 16 images x 1KB (64k x 64h, bf16 hi/lo)
#define XTOT (B_ * T_ * N_ * D_)   // 1,441,792

typedef __attribute__((ext_vector_type(8))) short short8;
typedef __attribute__((ext_vector_type(4))) float float4v;

// workspace layout (16B-aligned sections)
#define ERRWS_BYTES  ((size_t)(M_ * N_ * E_) * 4)          // 664,576
#define WIMG_OFF     (ERRWS_BYTES)
#define WIMG_BYTES   ((size_t)NE_ * NCHUNK * CHUNK_BYTES)  // 63,438,848
#define XH_OFF       (WIMG_OFF + WIMG_BYTES)
#define XIMG_BYTES   ((size_t)XTOT * 2)                    // 2,883,584
#define XL_OFF       (XH_OFF + XIMG_BYTES)

// Round-to-nearest bf16 hi + truncated bf16 of residual. Combined rel err ~2^-16.
__device__ inline void split2(float f, unsigned& hi, unsigned& lo) {
    unsigned u = __float_as_uint(f);
    unsigned r = (u + 0x7fffu + ((u >> 16) & 1u)) & 0xffff0000u;
    hi = r >> 16;
    float rem = f - __uint_as_float(r);
    lo = __float_as_uint(rem) >> 16;
}

// ---------------------------------------------------------------------------
// Precompute 1: W1/W2/W3 -> bf16 hi/lo fragment images.
__global__ __launch_bounds__(256) void wimg_kernel(
    const float* __restrict__ W1, const float* __restrict__ W2,
    const float* __restrict__ W3, char* __restrict__ wimg)
{
    int tid = blockIdx.x * 256 + threadIdx.x;
    int L  = tid & 63;
    int cf = (tid >> 6) & 3;
    int s2 = (tid >> 8) & 1;
    int v  = tid >> 9;
    int chunk = v % NCHUNK;
    int ne    = v / NCHUNK;
    if (ne >= NE_) return;

    const float* src;
    if (chunk < 20)       src = W1 + ((size_t)ne * 1280 + (size_t)chunk * 64) * 64;
    else if (chunk == 20) src = W2 + (size_t)ne * 4096;
    else                  src = W3 + (size_t)ne * 4096;

    int k0  = s2 * 32 + (L >> 4) * 8;
    int col = cf * 16 + (L & 15);

    unsigned hi[8], lo[8];
    #pragma unroll
    for (int j = 0; j < 8; ++j) {
        split2(src[(size_t)(k0 + j) * 64 + col], hi[j], lo[j]);
    }
    uint4 h4, l4;
    h4.x = hi[0] | (hi[1] << 16); h4.y = hi[2] | (hi[3] << 16);
    h4.z = hi[4] | (hi[5] << 16); h4.w = hi[6] | (hi[7] << 16);
    l4.x = lo[0] | (lo[1] << 16); l4.y = lo[2] | (lo[3] << 16);
    l4.z = lo[4] | (lo[5] << 16); l4.w = lo[6] | (lo[7] << 16);

    char* base = wimg + ((size_t)(ne * NCHUNK + chunk)) * CHUNK_BYTES
                      + (size_t)((s2 * 4 + cf) * 2) * 1024 + (size_t)L * 16;
    *(uint4*)base          = h4;
    *(uint4*)(base + 1024) = l4;
}

// ---------------------------------------------------------------------------
// Precompute 2: x -> bf16 hi/lo images (same linear layout as x).
__global__ __launch_bounds__(256) void xsplit_kernel(
    const float* __restrict__ x, short* __restrict__ xh, short* __restrict__ xl)
{
    int i = (blockIdx.x * 256 + threadIdx.x) * 4;
    if (i >= XTOT) return;
    float4 v = *(const float4*)(x + i);
    unsigned h0, h1, h2, h3, l0, l1, l2, l3;
    split2(v.x, h0, l0); split2(v.y, h1, l1);
    split2(v.z, h2, l2); split2(v.w, h3, l3);
    uint2 hp, lp;
    hp.x = h0 | (h1 << 16); hp.y = h2 | (h3 << 16);
    lp.x = l0 | (l1 << 16); lp.y = l2 | (l3 << 16);
    *(uint2*)(xh + i) = hp;
    *(uint2*)(xl + i) = lp;
}

// ---------------------------------------------------------------------------
// Main kernel. Block = (n, e, mtile), swizzled g = e + 8*mt + 64*n so all 8
// mtiles of one (n,e) share an XCD (g%8 == e). 4 waves, 32 rows x 64 cols each.
// launch_bounds(256,2): 256 unified regs/wave -> no scratch spill (R4 lesson).
__global__ __launch_bounds__(256, 2) void moe_err_kernel(
    const float* __restrict__ x, const short* __restrict__ xh,
    const short* __restrict__ xl, const int* __restrict__ nb,
    const float* __restrict__ b1, const float* __restrict__ b2,
    const float* __restrict__ b3, const char* __restrict__ wimg,
    float* __restrict__ err_ws)
{
    const int tid = threadIdx.x;
    const int w   = tid >> 6;
    const int L   = tid & 63;
    const int g   = blockIdx.x;
    const int e  = g & 7;
    const int mt = (g >> 3) & 7;
    const int n  = g >> 6;
    const int ne = n * E_ + e;

    __shared__ __align__(16) unsigned char wbuf[CHUNK_BYTES];   // 16 KB
    __shared__ __align__(16) short h1h[128][72];                // 18,432 B
    __shared__ __align__(16) short h1l[128][72];                // 18,432 B

    const int lrow    = L & 15;
    const int dseg    = (L >> 4) * 8;
    const int rowbase = mt * MT2 + w * 32;

    // per-rowtile lane row -> base into x images
    const short* xhrow[2];
    const short* xlrow[2];
    #pragma unroll
    for (int rt = 0; rt < 2; ++rt) {
        int m  = rowbase + rt * 16 + lrow;
        int mc = m < M_ ? m : M_ - 1;
        int b = mc / TW, t = mc % TW;
        size_t base = (size_t)(b * T_ + t) * N_ * D_;
        xhrow[rt] = xh + base;
        xlrow[rt] = xl + base;
    }

    int nn[K_];
    #pragma unroll
    for (int k = 0; k < K_; ++k) nn[k] = nb[n * K_ + k];

    const char* wsrc = wimg + (size_t)ne * NCHUNK * CHUNK_BYTES;

    // W chunk register prefetch: wave w stages images 4w..4w+3
    uint4 wreg[4];
    auto loadW = [&](int chunk) {
        const uint4* wp = (const uint4*)(wsrc + (size_t)chunk * CHUNK_BYTES);
        #pragma unroll
        for (int i = 0; i < 4; ++i) wreg[i] = wp[(w * 4 + i) * 64 + L];
    };
    auto storeW = [&]() {
        uint4* lp = (uint4*)wbuf;
        #pragma unroll
        for (int i = 0; i < 4; ++i) lp[(w * 4 + i) * 64 + L] = wreg[i];
    };
    auto bfrag = [&](int s2, int cf, int hl) -> short8 {
        return *(const short8*)(wbuf + (size_t)((s2 * 4 + cf) * 2 + hl) * 1024
                                     + (size_t)L * 16);
    };

    float4v acc1[2][4];
    #pragma unroll
    for (int rt = 0; rt < 2; ++rt)
        #pragma unroll
        for (int cf = 0; cf < 4; ++cf) acc1[rt][cf] = (float4v)0.f;

    loadW(0);

    // ---------------- GEMM1: 20 chunks of K=64 ----------------
    for (int c = 0; c < 20; ++c) {
        __syncthreads();            // prior chunk's B-reads done
        storeW();
        __syncthreads();            // images visible

        const int dt = c >> 2, kk = c & 3;
        const int off = (dt * N_ + nn[kk]) * D_;

        if (c < 19) loadW(c + 1);   // prefetch next chunk during MFMAs

        #pragma unroll
        for (int s2 = 0; s2 < 2; ++s2) {
            short8 ah[2], al[2];
            #pragma unroll
            for (int rt = 0; rt < 2; ++rt) {
                ah[rt] = *(const short8*)(xhrow[rt] + off + s2 * 32 + dseg);
                al[rt] = *(const short8*)(xlrow[rt] + off + s2 * 32 + dseg);
            }
            #pragma unroll
            for (int cf = 0; cf < 4; ++cf) {
                short8 bh = bfrag(s2, cf, 0);
                short8 bl = bfrag(s2, cf, 1);
                #pragma unroll
                for (int rt = 0; rt < 2; ++rt) {
                    acc1[rt][cf] = __builtin_amdgcn_mfma_f32_16x16x32_bf16(ah[rt], bh, acc1[rt][cf], 0, 0, 0);
                    acc1[rt][cf] = __builtin_amdgcn_mfma_f32_16x16x32_bf16(ah[rt], bl, acc1[rt][cf], 0, 0, 0);
                    acc1[rt][cf] = __builtin_amdgcn_mfma_f32_16x16x32_bf16(al[rt], bh, acc1[rt][cf], 0, 0, 0);
                }
            }
        }
    }

    // ---------------- h1 = relu(acc1 + b1) -> split bf16 LDS; stage W2 ------
    loadW(20);
    __syncthreads();                // last chunk's B-reads done
    storeW();
    const int ccol = L & 15;
    const int qrow = (L >> 4) * 4;
    #pragma unroll
    for (int cf = 0; cf < 4; ++cf) {
        float bv = b1[(size_t)ne * H_ + cf * 16 + ccol];
        #pragma unroll
        for (int rt = 0; rt < 2; ++rt)
            #pragma unroll
            for (int reg = 0; reg < 4; ++reg) {
                int r = w * 32 + rt * 16 + qrow + reg;      // wave-private rows
                float hv = fmaxf(acc1[rt][cf][reg] + bv, 0.f);
                unsigned hi, lo;
                split2(hv, hi, lo);
                h1h[r][cf * 16 + ccol] = (short)hi;
                h1l[r][cf * 16 + ccol] = (short)lo;
            }
    }
    __syncthreads();                // W2 images visible (h rows are wave-private)

    // ---------------- GEMM2: h1 @ W2 (K=64) ----------------
    float4v acc2[2][4];
    #pragma unroll
    for (int rt = 0; rt < 2; ++rt)
        #pragma unroll
        for (int cf = 0; cf < 4; ++cf) acc2[rt][cf] = (float4v)0.f;

    loadW(21);                      // prefetch W3 during GEMM2 MFMAs
    #pragma unroll
    for (int s2 = 0; s2 < 2; ++s2) {
        short8 ah[2], al[2];
        #pragma unroll
        for (int rt = 0; rt < 2; ++rt) {
            ah[rt] = *(const short8*)&h1h[w * 32 + rt * 16 + lrow][s2 * 32 + dseg];
            al[rt] = *(const short8*)&h1l[w * 32 + rt * 16 + lrow][s2 * 32 + dseg];
        }
        #pragma unroll
        for (int cf = 0; cf < 4; ++cf) {
            short8 bh = bfrag(s2, cf, 0);
            short8 bl = bfrag(s2, cf, 1);
            #pragma unroll
            for (int rt = 0; rt < 2; ++rt) {
                acc2[rt][cf] = __builtin_amdgcn_mfma_f32_16x16x32_bf16(ah[rt], bh, acc2[rt][cf], 0, 0, 0);
                acc2[rt][cf] = __builtin_amdgcn_mfma_f32_16x16x32_bf16(ah[rt], bl, acc2[rt][cf], 0, 0, 0);
                acc2[rt][cf] = __builtin_amdgcn_mfma_f32_16x16x32_bf16(al[rt], bh, acc2[rt][cf], 0, 0, 0);
            }
        }
    }

    // ---------------- h2 = relu(acc2 + b2) -> split bf16 LDS; stage W3 ------
    __syncthreads();                // all waves done reading W2 images
    storeW();
    #pragma unroll
    for (int cf = 0; cf < 4; ++cf) {
        float bv = b2[(size_t)ne * H_ + cf * 16 + ccol];
        #pragma unroll
        for (int rt = 0; rt < 2; ++rt)
            #pragma unroll
            for (int reg = 0; reg < 4; ++reg) {
                int r = w * 32 + rt * 16 + qrow + reg;
                float hv = fmaxf(acc2[rt][cf][reg] + bv, 0.f);
                unsigned hi, lo;
                split2(hv, hi, lo);
                h1h[r][cf * 16 + ccol] = (short)hi;
                h1l[r][cf * 16 + ccol] = (short)lo;
            }
    }
    __syncthreads();                // W3 images visible

    // ---------------- GEMM3: h2 @ W3 -> pred; err epilogue ----------------
    float4v acc3[2][4];
    #pragma unroll
    for (int rt = 0; rt < 2; ++rt)
        #pragma unroll
        for (int cf = 0; cf < 4; ++cf) acc3[rt][cf] = (float4v)0.f;

    #pragma unroll
    for (int s2 = 0; s2 < 2; ++s2) {
        short8 ah[2], al[2];
        #pragma unroll
        for (int rt = 0; rt < 2; ++rt) {
            ah[rt] = *(const short8*)&h1h[w * 32 + rt * 16 + lrow][s2 * 32 + dseg];
            al[rt] = *(const short8*)&h1l[w * 32 + rt * 16 + lrow][s2 * 32 + dseg];
        }
        #pragma unroll
        for (int cf = 0; cf < 4; ++cf) {
            short8 bh = bfrag(s2, cf, 0);
            short8 bl = bfrag(s2, cf, 1);
            #pragma unroll
            for (int rt = 0; rt < 2; ++rt) {
                acc3[rt][cf] = __builtin_amdgcn_mfma_f32_16x16x32_bf16(ah[rt], bh, acc3[rt][cf], 0, 0, 0);
                acc3[rt][cf] = __builtin_amdgcn_mfma_f32_16x16x32_bf16(ah[rt], bl, acc3[rt][cf], 0, 0, 0);
                acc3[rt][cf] = __builtin_amdgcn_mfma_f32_16x16x32_bf16(al[rt], bh, acc3[rt][cf], 0, 0, 0);
            }
        }
    }

    float b3v[4];
    #pragma unroll
    for (int cf = 0; cf < 4; ++cf) b3v[cf] = b3[(size_t)ne * D_ + cf * 16 + ccol];

    #pragma unroll
    for (int rt = 0; rt < 2; ++rt) {
        float s[4] = {0.f, 0.f, 0.f, 0.f};
        #pragma unroll
        for (int reg = 0; reg < 4; ++reg) {
            int m  = rowbase + rt * 16 + qrow + reg;
            int mc = m < M_ ? m : M_ - 1;
            int b = mc / TW, t = mc % TW;
            const float* yp = x + ((size_t)(b * T_ + t + 2) * N_ + n) * D_;
            #pragma unroll
            for (int cf = 0; cf < 4; ++cf) {
                float d = acc3[rt][cf][reg] + b3v[cf] - yp[cf * 16 + ccol];
                s[reg] += d * d;
            }
        }
        #pragma unroll
        for (int reg = 0; reg < 4; ++reg) {
            s[reg] += __shfl_xor(s[reg], 1);
            s[reg] += __shfl_xor(s[reg], 2);
            s[reg] += __shfl_xor(s[reg], 4);
            s[reg] += __shfl_xor(s[reg], 8);
        }
        if (ccol == 0) {
            #pragma unroll
            for (int reg = 0; reg < 4; ++reg) {
                int m = rowbase + rt * 16 + qrow + reg;
                if (m < M_) err_ws[((size_t)m * N_ + n) * E_ + e] = s[reg] * (1.f / 64.f);
            }
        }
    }
}

// ---------------------------------------------------------------------------
// Reduce: per (m,n) min/argmin over E, softmax(-err) KL; block atomicAdd.
__global__ __launch_bounds__(256) void moe_reduce_kernel(
    const float* __restrict__ err_ws, float* __restrict__ out)
{
    const int tid = threadIdx.x;
    const int idx = blockIdx.x * 256 + tid;
    float v = 0.f;
    if (idx < M_ * N_) {
        const int m = idx / N_, n = idx % N_;
        const float* ep = err_ws + (size_t)idx * E_;
        float ev[E_];
        float mn = ep[0];
        int am = 0;
        ev[0] = mn;
        #pragma unroll
        for (int i = 1; i < E_; ++i) {
            ev[i] = ep[i];
            if (ev[i] < mn) { mn = ev[i]; am = i; }
        }
        float p[E_];
        float Z = 0.f;
        #pragma unroll
        for (int i = 0; i < E_; ++i) { p[i] = expf(mn - ev[i]); Z += p[i]; }
        const float invZ = 1.f / Z;
        float kl = 0.f;
        #pragma unroll
        for (int i = 0; i < E_; ++i) {
            float q = p[i] * invZ;
            kl += q * (logf(q + 1e-9f) + 2.0794415416798357f);  // log(8)
        }
        v = mn + 0.01f * kl;
        const int t = m % TW, b = m / TW;
        if (t == TW - 1 && n == N_ - 1) out[1 + b] = (float)am;
    }
    __shared__ float sd[256];
    sd[tid] = v;
    __syncthreads();
    for (int s = 128; s > 0; s >>= 1) {
        if (tid < s) sd[tid] += sd[tid + s];
        __syncthreads();
    }
    if (tid == 0) atomicAdd(out, sd[0] * (1.f / 20160.f));  // / B / (N-1) / (T-4)
}

__global__ void init_out_kernel(float* out)
{
    if (threadIdx.x == 0) out[0] = 0.f;
}

extern "C" void kernel_launch(void* const* d_in, const int* in_sizes, int n_in,
                              void* d_out, int out_size, void* d_ws, size_t ws_size,
                              hipStream_t stream)
{
    const float* x  = (const float*)d_in[0];
    const int*   nb = (const int*)d_in[1];
    const float* W1 = (const float*)d_in[2];
    const float* b1 = (const float*)d_in[3];
    const float* W2 = (const float*)d_in[4];
    const float* b2 = (const float*)d_in[5];
    const float* W3 = (const float*)d_in[6];
    const float* b3 = (const float*)d_in[7];
    float* out    = (float*)d_out;
    float* err_ws = (float*)d_ws;
    char*  wimg   = (char*)d_ws + WIMG_OFF;
    short* xh     = (short*)((char*)d_ws + XH_OFF);
    short* xl     = (short*)((char*)d_ws + XL_OFF);

    hipLaunchKernelGGL(init_out_kernel, dim3(1), dim3(64), 0, stream, out);
    hipLaunchKernelGGL(wimg_kernel, dim3(7744), dim3(256), 0, stream, W1, W2, W3, wimg);
    hipLaunchKernelGGL(xsplit_kernel, dim3(1408), dim3(256), 0, stream, x, xh, xl);
    hipLaunchKernelGGL(moe_err_kernel, dim3(NE_ * 8), dim3(256), 0, stream,
                       x, xh, xl, nb, b1, b2, b3, wimg, err_ws);
    const int nred = (M_ * N_ + 255) / 256;
    hipLaunchKernelGGL(moe_reduce_kernel, dim3(nred), dim3(256), 0, stream, err_ws, out);
}

// Round 6
// 273.873 us; speedup vs baseline: 9.3150x; 1.4516x over previous
//
#include <hip/hip_runtime.h>
#include <math.h>

// Problem constants
#define B_   16
#define T_   64
#define N_   22
#define D_   64
#define K_   4
#define E_   8
#define H_   64
#define TW   59                 // valid time steps per batch (t=2..60 absolute)
#define M_   (B_ * TW)          // 944
#define NE_  (N_ * E_)          // 176
#define NDXT (N_ * D_)          // 1408 floats per (b,t) slice of x

typedef __attribute__((ext_vector_type(8))) short short8;
typedef __attribute__((ext_vector_type(4))) float float4v;

union Frag {
    short8 s8;
    uint2  h2[2];
    unsigned u[4];
};

// LDS layout (total 81,904 B -> 2 blocks/CU at 160 KB)
#define WBUF_OFF  0        // 16,384 B : 16 W images x 1 KB (hi/lo, pair-per-wave)
#define XH_OFF    16384    // 32,760 B : x-cache hi, [tt:63][k:4][d:64] + 4 pad, stride 260 shorts
#define XL_OFF    49144    // 32,760 B : x-cache lo
#define XROW      260      // shorts per tt row (4*64 + 4 pad; 520 B: b64-aligned, <=2-way banks)
#define HIMG_ROW  68       // dwords per h-image row (64 + 4 pad; 272 B: b128-aligned)

// ---------------------------------------------------------------------------
// Main kernel. Block = (n, e, bb): covers rows m = bb*59 .. bb*59+58 (64-padded).
// Swizzle g = e + 8*(bb + 16*n): all 16 bb-blocks of one (n,e) share an XCD.
// GEMM1: A from LDS x-cache (loaded once per block, split bf16 hi/lo);
// W streamed fp32 -> in-register trunc-split -> LDS images, 1 chunk ahead.
// GEMM2/3: A from packed h-images in LDS; same W path (W2, W3).
__global__ __launch_bounds__(256, 2) void moe_err_kernel(
    const float* __restrict__ x, const int* __restrict__ nb,
    const float* __restrict__ W1, const float* __restrict__ W2,
    const float* __restrict__ W3,
    const float* __restrict__ b1, const float* __restrict__ b2,
    const float* __restrict__ b3, float* __restrict__ err_ws)
{
    const int tid = threadIdx.x;
    const int w   = tid >> 6;
    const int L   = tid & 63;
    const int g   = blockIdx.x;
    const int e   = g & 7;
    const int bb  = (g >> 3) & 15;
    const int n   = g >> 7;
    const int ne  = n * E_ + e;

    __shared__ __align__(16) char smem[81904];
    unsigned char* wbuf = (unsigned char*)(smem + WBUF_OFF);
    short* xh = (short*)(smem + XH_OFF);
    short* xl = (short*)(smem + XL_OFF);
    unsigned* himg = (unsigned*)(smem + XH_OFF);   // reused after GEMM1

    const int lrow = L & 15;           // A row within 16
    const int dseg = (L >> 4) * 8;     // k-subsegment
    const int ccol = L & 15;           // C col within 16-group
    const int qrow = (L >> 4) * 4;     // C row quad base

    // neighbor nodes (wave-uniform)
    const int n0 = __builtin_amdgcn_readfirstlane(nb[n * K_ + 0]);
    const int n1 = __builtin_amdgcn_readfirstlane(nb[n * K_ + 1]);
    const int n2 = __builtin_amdgcn_readfirstlane(nb[n * K_ + 2]);
    const int n3 = __builtin_amdgcn_readfirstlane(nb[n * K_ + 3]);

    const float* W1ne = W1 + (size_t)ne * 1280 * 64;
    const float* W2ne = W2 + (size_t)ne * 4096;
    const float* W3ne = W3 + (size_t)ne * 4096;

    // ---- W pipeline: fp32 strided load -> trunc-split -> packed regs -> LDS.
    // Wave w owns image pairs 2w, 2w+1 (pair = s2*4+cf).
    float wf[2][8];
    uint4 wph[2], wpl[2];
    auto loadWf = [&](const float* src) {
        #pragma unroll
        for (int p = 0; p < 2; ++p) {
            const int pi = 2 * w + p;
            const float* sp = src + ((pi >> 2) * 32 + (L >> 4) * 8) * 64
                                  + ((pi & 3) * 16 + (L & 15));
            #pragma unroll
            for (int j = 0; j < 8; ++j) wf[p][j] = sp[j * 64];
        }
    };
    auto packW = [&]() {
        #pragma unroll
        for (int p = 0; p < 2; ++p) {
            unsigned hs[8], ls[8];
            #pragma unroll
            for (int j = 0; j < 8; ++j) {
                unsigned u  = __float_as_uint(wf[p][j]);
                unsigned ht = u & 0xffff0000u;
                float rem   = wf[p][j] - __uint_as_float(ht);
                hs[j] = u >> 16;
                ls[j] = __float_as_uint(rem) >> 16;
            }
            wph[p].x = hs[0] | (hs[1] << 16); wph[p].y = hs[2] | (hs[3] << 16);
            wph[p].z = hs[4] | (hs[5] << 16); wph[p].w = hs[6] | (hs[7] << 16);
            wpl[p].x = ls[0] | (ls[1] << 16); wpl[p].y = ls[2] | (ls[3] << 16);
            wpl[p].z = ls[4] | (ls[5] << 16); wpl[p].w = ls[6] | (ls[7] << 16);
        }
    };
    auto storeW = [&]() {
        #pragma unroll
        for (int p = 0; p < 2; ++p) {
            char* bp = (char*)wbuf + (size_t)(2 * w + p) * 2048 + (size_t)L * 16;
            *(uint4*)bp          = wph[p];
            *(uint4*)(bp + 1024) = wpl[p];
        }
    };
    auto bfrag = [&](int s2, int cf, int hl) -> short8 {
        return *(const short8*)(wbuf + (size_t)((s2 * 4 + cf) * 2 + hl) * 1024
                                     + (size_t)L * 16);
    };

    // ---- issue W chunk 0 loads, then stage the x-cache ----------------------
    loadWf(W1ne);

    {
        const float* xb = x + (size_t)(bb * T_) * NDXT;   // [tt][node][d]
        #pragma unroll
        for (int it = 0; it < 16; ++it) {
            int i = tid + it * 256;                       // float4 index, < 4032
            if (i < 63 * 4 * 16) {
                int rr = i >> 4, d4 = i & 15;
                int tt = rr >> 2, k = rr & 3;
                int nk = (k == 0) ? n0 : ((k == 1) ? n1 : ((k == 2) ? n2 : n3));
                float4 v = *(const float4*)(xb + ((size_t)tt * N_ + nk) * D_ + d4 * 4);
                float f[4] = {v.x, v.y, v.z, v.w};
                unsigned hs[4], ls[4];
                #pragma unroll
                for (int j = 0; j < 4; ++j) {
                    unsigned u  = __float_as_uint(f[j]);
                    unsigned ht = u & 0xffff0000u;
                    float rem   = f[j] - __uint_as_float(ht);
                    hs[j] = u >> 16;
                    ls[j] = __float_as_uint(rem) >> 16;
                }
                uint2 hh, ll;
                hh.x = hs[0] | (hs[1] << 16); hh.y = hs[2] | (hs[3] << 16);
                ll.x = ls[0] | (ls[1] << 16); ll.y = ls[2] | (ls[3] << 16);
                int o = tt * XROW + k * 64 + d4 * 4;
                *(uint2*)(xh + o) = hh;
                *(uint2*)(xl + o) = ll;
            }
        }
    }
    packW();                          // waits chunk-0 W loads

    const int tc = (w * 16 + lrow) < 58 ? (w * 16 + lrow) : 58;  // clamped t row

    float4v acc1[4];
    #pragma unroll
    for (int cf = 0; cf < 4; ++cf) acc1[cf] = (float4v)0.f;

    // ---------------- GEMM1: 20 chunks of K=64 (fully unrolled) -------------
    #pragma unroll
    for (int dt = 0; dt < 5; ++dt) {
        #pragma unroll
        for (int kk = 0; kk < 4; ++kk) {
            const int c = dt * 4 + kk;
            __syncthreads();          // prev chunk's B-reads (and iter0: x-cache) done
            storeW();
            __syncthreads();          // images visible

            const float* nsrc = (c < 19) ? (W1ne + (size_t)(c + 1) * 4096) : W2ne;
            loadWf(nsrc);             // prefetch next W during MFMAs

            #pragma unroll
            for (int s2 = 0; s2 < 2; ++s2) {
                const int ao = (tc + dt) * XROW + kk * 64 + s2 * 32 + dseg;
                Frag ah, al;
                ah.h2[0] = *(const uint2*)(xh + ao);
                ah.h2[1] = *(const uint2*)(xh + ao + 4);
                al.h2[0] = *(const uint2*)(xl + ao);
                al.h2[1] = *(const uint2*)(xl + ao + 4);
                #pragma unroll
                for (int cf = 0; cf < 4; ++cf) {
                    short8 bh = bfrag(s2, cf, 0);
                    short8 bl = bfrag(s2, cf, 1);
                    acc1[cf] = __builtin_amdgcn_mfma_f32_16x16x32_bf16(ah.s8, bh, acc1[cf], 0, 0, 0);
                    acc1[cf] = __builtin_amdgcn_mfma_f32_16x16x32_bf16(ah.s8, bl, acc1[cf], 0, 0, 0);
                    acc1[cf] = __builtin_amdgcn_mfma_f32_16x16x32_bf16(al.s8, bh, acc1[cf], 0, 0, 0);
                }
            }
            packW();                  // split next chunk (waits its loads)
        }
    }

    // ---------------- h1 = relu(acc1 + b1) -> packed h-image; stage W2 ------
    __syncthreads();                  // chunk19 B-reads + all x-cache reads done
    storeW();                         // W2 images
    loadWf(W3ne);                     // prefetch W3
    #pragma unroll
    for (int cf = 0; cf < 4; ++cf) {
        float bv = b1[(size_t)ne * H_ + cf * 16 + ccol];
        #pragma unroll
        for (int reg = 0; reg < 4; ++reg) {
            float hv = fmaxf(acc1[cf][reg] + bv, 0.f);
            unsigned u  = __float_as_uint(hv);
            unsigned ht = u & 0xffff0000u;
            float rem   = hv - __uint_as_float(ht);
            himg[(w * 16 + qrow + reg) * HIMG_ROW + cf * 16 + ccol] =
                ht | (__float_as_uint(rem) >> 16);
        }
    }
    packW();                          // split W3
    __syncthreads();                  // W2 images + h1 visible

    // ---------------- GEMM2: h1 @ W2 (K=64) ----------------
    float4v acc2[4];
    #pragma unroll
    for (int cf = 0; cf < 4; ++cf) acc2[cf] = (float4v)0.f;
    {
        const int rr = w * 16 + lrow;
        #pragma unroll
        for (int s2 = 0; s2 < 2; ++s2) {
            uint4 u0 = *(const uint4*)(himg + rr * HIMG_ROW + s2 * 32 + dseg);
            uint4 u1 = *(const uint4*)(himg + rr * HIMG_ROW + s2 * 32 + dseg + 4);
            unsigned uu[8] = {u0.x, u0.y, u0.z, u0.w, u1.x, u1.y, u1.z, u1.w};
            Frag ah, al;
            #pragma unroll
            for (int i = 0; i < 4; ++i) {
                ah.u[i] = (uu[2 * i] >> 16) | (uu[2 * i + 1] & 0xffff0000u);
                al.u[i] = (uu[2 * i] & 0xffffu) | (uu[2 * i + 1] << 16);
            }
            #pragma unroll
            for (int cf = 0; cf < 4; ++cf) {
                short8 bh = bfrag(s2, cf, 0);
                short8 bl = bfrag(s2, cf, 1);
                acc2[cf] = __builtin_amdgcn_mfma_f32_16x16x32_bf16(ah.s8, bh, acc2[cf], 0, 0, 0);
                acc2[cf] = __builtin_amdgcn_mfma_f32_16x16x32_bf16(ah.s8, bl, acc2[cf], 0, 0, 0);
                acc2[cf] = __builtin_amdgcn_mfma_f32_16x16x32_bf16(al.s8, bh, acc2[cf], 0, 0, 0);
            }
        }
    }

    // ---------------- h2 = relu(acc2 + b2) -> h-image; stage W3 -------------
    __syncthreads();                  // W2 image + h1 reads done
    storeW();                         // W3 images
    #pragma unroll
    for (int cf = 0; cf < 4; ++cf) {
        float bv = b2[(size_t)ne * H_ + cf * 16 + ccol];
        #pragma unroll
        for (int reg = 0; reg < 4; ++reg) {
            float hv = fmaxf(acc2[cf][reg] + bv, 0.f);
            unsigned u  = __float_as_uint(hv);
            unsigned ht = u & 0xffff0000u;
            float rem   = hv - __uint_as_float(ht);
            himg[(w * 16 + qrow + reg) * HIMG_ROW + cf * 16 + ccol] =
                ht | (__float_as_uint(rem) >> 16);
        }
    }
    __syncthreads();                  // W3 images + h2 visible

    // ---------------- GEMM3: h2 @ W3 -> pred; err epilogue ------------------
    float4v acc3[4];
    #pragma unroll
    for (int cf = 0; cf < 4; ++cf) acc3[cf] = (float4v)0.f;
    {
        const int rr = w * 16 + lrow;
        #pragma unroll
        for (int s2 = 0; s2 < 2; ++s2) {
            uint4 u0 = *(const uint4*)(himg + rr * HIMG_ROW + s2 * 32 + dseg);
            uint4 u1 = *(const uint4*)(himg + rr * HIMG_ROW + s2 * 32 + dseg + 4);
            unsigned uu[8] = {u0.x, u0.y, u0.z, u0.w, u1.x, u1.y, u1.z, u1.w};
            Frag ah, al;
            #pragma unroll
            for (int i = 0; i < 4; ++i) {
                ah.u[i] = (uu[2 * i] >> 16) | (uu[2 * i + 1] & 0xffff0000u);
                al.u[i] = (uu[2 * i] & 0xffffu) | (uu[2 * i + 1] << 16);
            }
            #pragma unroll
            for (int cf = 0; cf < 4; ++cf) {
                short8 bh = bfrag(s2, cf, 0);
                short8 bl = bfrag(s2, cf, 1);
                acc3[cf] = __builtin_amdgcn_mfma_f32_16x16x32_bf16(ah.s8, bh, acc3[cf], 0, 0, 0);
                acc3[cf] = __builtin_amdgcn_mfma_f32_16x16x32_bf16(ah.s8, bl, acc3[cf], 0, 0, 0);
                acc3[cf] = __builtin_amdgcn_mfma_f32_16x16x32_bf16(al.s8, bh, acc3[cf], 0, 0, 0);
            }
        }
    }

    {
        float b3v[4];
        #pragma unroll
        for (int cf = 0; cf < 4; ++cf) b3v[cf] = b3[(size_t)ne * D_ + cf * 16 + ccol];

        #pragma unroll
        for (int reg = 0; reg < 4; ++reg) {
            const int t = w * 16 + qrow + reg;         // 0..63; valid <= 58
            float s = 0.f;
            if (t <= 58) {
                const float* yp = x + ((size_t)(bb * T_ + t + 2) * N_ + n) * D_;
                #pragma unroll
                for (int cf = 0; cf < 4; ++cf) {
                    float d = acc3[cf][reg] + b3v[cf] - yp[cf * 16 + ccol];
                    s += d * d;
                }
            }
            s += __shfl_xor(s, 1);
            s += __shfl_xor(s, 2);
            s += __shfl_xor(s, 4);
            s += __shfl_xor(s, 8);
            if (ccol == 0 && t <= 58) {
                int m = bb * TW + t;
                err_ws[((size_t)m * N_ + n) * E_ + e] = s * (1.f / 64.f);
            }
        }
    }
}

// ---------------------------------------------------------------------------
// Reduce: per (m,n) min/argmin over E, softmax(-err) KL; block atomicAdd.
__global__ __launch_bounds__(256) void moe_reduce_kernel(
    const float* __restrict__ err_ws, float* __restrict__ out)
{
    const int tid = threadIdx.x;
    const int idx = blockIdx.x * 256 + tid;
    float v = 0.f;
    if (idx < M_ * N_) {
        const int m = idx / N_, n = idx % N_;
        const float* ep = err_ws + (size_t)idx * E_;
        float ev[E_];
        float mn = ep[0];
        int am = 0;
        ev[0] = mn;
        #pragma unroll
        for (int i = 1; i < E_; ++i) {
            ev[i] = ep[i];
            if (ev[i] < mn) { mn = ev[i]; am = i; }
        }
        float p[E_];
        float Z = 0.f;
        #pragma unroll
        for (int i = 0; i < E_; ++i) { p[i] = expf(mn - ev[i]); Z += p[i]; }
        const float invZ = 1.f / Z;
        float kl = 0.f;
        #pragma unroll
        for (int i = 0; i < E_; ++i) {
            float q = p[i] * invZ;
            kl += q * (logf(q + 1e-9f) + 2.0794415416798357f);  // log(8)
        }
        v = mn + 0.01f * kl;
        const int t = m % TW, b = m / TW;
        if (t == TW - 1 && n == N_ - 1) out[1 + b] = (float)am;
    }
    __shared__ float sd[256];
    sd[tid] = v;
    __syncthreads();
    for (int s = 128; s > 0; s >>= 1) {
        if (tid < s) sd[tid] += sd[tid + s];
        __syncthreads();
    }
    if (tid == 0) atomicAdd(out, sd[0] * (1.f / 20160.f));  // / B / (N-1) / (T-4)
}

__global__ void init_out_kernel(float* out)
{
    if (threadIdx.x == 0) out[0] = 0.f;
}

extern "C" void kernel_launch(void* const* d_in, const int* in_sizes, int n_in,
                              void* d_out, int out_size, void* d_ws, size_t ws_size,
                              hipStream_t stream)
{
    const float* x  = (const float*)d_in[0];
    const int*   nb = (const int*)d_in[1];
    const float* W1 = (const float*)d_in[2];
    const float* b1 = (const float*)d_in[3];
    const float* W2 = (const float*)d_in[4];
    const float* b2 = (const float*)d_in[5];
    const float* W3 = (const float*)d_in[6];
    const float* b3 = (const float*)d_in[7];
    float* out    = (float*)d_out;
    float* err_ws = (float*)d_ws;    // 664,576 B — only ws use

    hipLaunchKernelGGL(init_out_kernel, dim3(1), dim3(64), 0, stream, out);
    hipLaunchKernelGGL(moe_err_kernel, dim3(NE_ * B_), dim3(256), 0, stream,
                       x, nb, W1, W2, W3, b1, b2, b3, err_ws);
    const int nred = (M_ * N_ + 255) / 256;
    hipLaunchKernelGGL(moe_reduce_kernel, dim3(nred), dim3(256), 0, stream, err_ws, out);
}

// Round 7
// 254.860 us; speedup vs baseline: 10.0099x; 1.0746x over previous
//
#include <hip/hip_runtime.h>
#include <math.h>

// Problem constants
#define B_   16
#define T_   64
#define N_   22
#define D_   64
#define K_   4
#define E_   8
#define H_   64
#define TW   59                 // valid time steps per batch (t=2..60 absolute)
#define M_   (B_ * TW)          // 944
#define NE_  (N_ * E_)          // 176
#define NDXT (N_ * D_)          // 1408
#define XTOT (B_ * T_ * N_ * D_)   // 1,441,792

typedef __attribute__((ext_vector_type(8))) short short8;
typedef __attribute__((ext_vector_type(4))) float float4v;

union Frag {
    short8 s8;
    unsigned u[4];
};

// workspace layout
#define ERRWS_BYTES  ((size_t)(M_ * N_ * E_) * 4)          // 664,576
#define XH_OFF       (ERRWS_BYTES)
#define XIMG_BYTES   ((size_t)XTOT * 2)                    // 2,883,584
#define XL_OFF       (XH_OFF + XIMG_BYTES)

#define HIMG_ROW 68        // dwords per h-image row (64 + 4 pad)

// Round-to... trunc-split: hi = trunc bf16, lo = trunc bf16 of residual.
__device__ inline void split2(float f, unsigned& hi, unsigned& lo) {
    unsigned u  = __float_as_uint(f);
    unsigned ht = u & 0xffff0000u;
    float rem   = f - __uint_as_float(ht);
    hi = u >> 16;
    lo = __float_as_uint(rem) >> 16;
}

// ---------------------------------------------------------------------------
// Precompute: x -> bf16 hi/lo images (same linear layout as x). ~17 MB traffic.
__global__ __launch_bounds__(256) void xsplit_kernel(
    const float* __restrict__ x, short* __restrict__ xh, short* __restrict__ xl)
{
    int i = (blockIdx.x * 256 + threadIdx.x) * 4;
    if (i >= XTOT) return;
    float4 v = *(const float4*)(x + i);
    unsigned h0, h1, h2, h3, l0, l1, l2, l3;
    split2(v.x, h0, l0); split2(v.y, h1, l1);
    split2(v.z, h2, l2); split2(v.w, h3, l3);
    uint2 hp, lp;
    hp.x = h0 | (h1 << 16); hp.y = h2 | (h3 << 16);
    lp.x = l0 | (l1 << 16); lp.y = l2 | (l3 << 16);
    *(uint2*)(xh + i) = hp;
    *(uint2*)(xl + i) = lp;
}

// ---------------------------------------------------------------------------
// Main kernel. Block = (n, e, mtile of 128 rows); swizzle g = e + 8*mt + 64*n
// so all 8 mtiles of one (n,e) share an XCD. 4 waves, each 32 rows x 64 cols
// (rt=2 row-tiles -> each LDS B-read feeds 2x MFMAs vs R6).
// A: direct global 16B loads from pre-split xh/xl (L2-hot).
// W: fp32 stream -> in-register trunc-split -> LDS images, 1 chunk ahead.
// Hygiene (R4/R6 lesson): no runtime-indexed local arrays, ternary selects.
__global__ __launch_bounds__(256, 3) void moe_err_kernel(
    const float* __restrict__ x, const short* __restrict__ xh,
    const short* __restrict__ xl, const int* __restrict__ nb,
    const float* __restrict__ W1, const float* __restrict__ W2,
    const float* __restrict__ W3,
    const float* __restrict__ b1, const float* __restrict__ b2,
    const float* __restrict__ b3, float* __restrict__ err_ws)
{
    const int tid = threadIdx.x;
    const int w   = tid >> 6;
    const int L   = tid & 63;
    const int g   = blockIdx.x;
    const int e   = g & 7;
    const int mt  = (g >> 3) & 7;
    const int n   = g >> 6;
    const int ne  = n * E_ + e;

    __shared__ __align__(16) char smem[51200];     // 3 blocks/CU
    unsigned char* wbuf = (unsigned char*)smem;    // 16 KB: 16 W images x 1 KB
    unsigned* himg = (unsigned*)(smem + 16384);    // 34,816 B: 128 x 68 dwords

    const int lrow = L & 15;           // A row within 16
    const int dseg = (L >> 4) * 8;     // k-subsegment
    const int ccol = L & 15;           // C col within 16-group
    const int qrow = (L >> 4) * 4;     // C row quad base
    const int rowbase = mt * 128 + w * 32;

    // per-rowtile lane row -> base into x images
    const short* xhrow[2];
    const short* xlrow[2];
    #pragma unroll
    for (int rt = 0; rt < 2; ++rt) {
        int m  = rowbase + rt * 16 + lrow;
        int mc = m < M_ ? m : M_ - 1;
        int b = mc / TW, t = mc % TW;
        size_t base = (size_t)(b * T_ + t) * NDXT;
        xhrow[rt] = xh + base;
        xlrow[rt] = xl + base;
    }

    // neighbor offsets (wave-uniform scalars)
    const int o0 = __builtin_amdgcn_readfirstlane(nb[n * K_ + 0]) * D_;
    const int o1 = __builtin_amdgcn_readfirstlane(nb[n * K_ + 1]) * D_;
    const int o2 = __builtin_amdgcn_readfirstlane(nb[n * K_ + 2]) * D_;
    const int o3 = __builtin_amdgcn_readfirstlane(nb[n * K_ + 3]) * D_;

    const float* W1ne = W1 + (size_t)ne * (1280 * 64);
    const float* W2ne = W2 + (size_t)ne * 4096;
    const float* W3ne = W3 + (size_t)ne * 4096;

    // ---- W pipeline: fp32 strided load -> trunc-split -> packed regs -> LDS.
    // Wave w owns image pairs 2w, 2w+1 (pair = s2*4+cf).
    float wf[2][8];
    uint4 wph[2], wpl[2];
    auto loadWf = [&](const float* src) {
        #pragma unroll
        for (int p = 0; p < 2; ++p) {
            const int pi = 2 * w + p;
            const float* sp = src + ((pi >> 2) * 32 + (L >> 4) * 8) * 64
                                  + ((pi & 3) * 16 + (L & 15));
            #pragma unroll
            for (int j = 0; j < 8; ++j) wf[p][j] = sp[j * 64];
        }
    };
    auto packW = [&]() {
        #pragma unroll
        for (int p = 0; p < 2; ++p) {
            unsigned hs[8], ls[8];
            #pragma unroll
            for (int j = 0; j < 8; ++j) split2(wf[p][j], hs[j], ls[j]);
            wph[p].x = hs[0] | (hs[1] << 16); wph[p].y = hs[2] | (hs[3] << 16);
            wph[p].z = hs[4] | (hs[5] << 16); wph[p].w = hs[6] | (hs[7] << 16);
            wpl[p].x = ls[0] | (ls[1] << 16); wpl[p].y = ls[2] | (ls[3] << 16);
            wpl[p].z = ls[4] | (ls[5] << 16); wpl[p].w = ls[6] | (ls[7] << 16);
        }
    };
    auto storeW = [&]() {
        #pragma unroll
        for (int p = 0; p < 2; ++p) {
            char* bp = (char*)wbuf + (size_t)(2 * w + p) * 2048 + (size_t)L * 16;
            *(uint4*)bp          = wph[p];
            *(uint4*)(bp + 1024) = wpl[p];
        }
    };
    auto bfrag = [&](int s2, int cf, int hl) -> short8 {
        return *(const short8*)(wbuf + (size_t)((s2 * 4 + cf) * 2 + hl) * 1024
                                     + (size_t)L * 16);
    };

    loadWf(W1ne);
    packW();

    float4v acc1[2][4];
    #pragma unroll
    for (int rt = 0; rt < 2; ++rt)
        #pragma unroll
        for (int cf = 0; cf < 4; ++cf) acc1[rt][cf] = (float4v)0.f;

    // ---------------- GEMM1: 20 chunks of K=64 ----------------
    for (int dt = 0; dt < 5; ++dt) {
        #pragma unroll
        for (int kk = 0; kk < 4; ++kk) {
            const int c = dt * 4 + kk;
            __syncthreads();          // prev chunk's B-reads done
            storeW();
            __syncthreads();          // images visible

            const float* nsrc = (c < 19) ? (W1ne + (size_t)(c + 1) * 4096) : W2ne;
            loadWf(nsrc);             // prefetch next W during A-loads + MFMAs

            const int okk = (kk == 0) ? o0 : ((kk == 1) ? o1 : ((kk == 2) ? o2 : o3));
            const int off = dt * NDXT + okk;

            Frag ah[2][2], al[2][2];  // [s2][rt]
            #pragma unroll
            for (int s2 = 0; s2 < 2; ++s2)
                #pragma unroll
                for (int rt = 0; rt < 2; ++rt) {
                    ah[s2][rt].s8 = *(const short8*)(xhrow[rt] + off + s2 * 32 + dseg);
                    al[s2][rt].s8 = *(const short8*)(xlrow[rt] + off + s2 * 32 + dseg);
                }
            #pragma unroll
            for (int s2 = 0; s2 < 2; ++s2)
                #pragma unroll
                for (int cf = 0; cf < 4; ++cf) {
                    short8 bh = bfrag(s2, cf, 0);
                    short8 bl = bfrag(s2, cf, 1);
                    #pragma unroll
                    for (int rt = 0; rt < 2; ++rt) {
                        acc1[rt][cf] = __builtin_amdgcn_mfma_f32_16x16x32_bf16(ah[s2][rt].s8, bh, acc1[rt][cf], 0, 0, 0);
                        acc1[rt][cf] = __builtin_amdgcn_mfma_f32_16x16x32_bf16(ah[s2][rt].s8, bl, acc1[rt][cf], 0, 0, 0);
                        acc1[rt][cf] = __builtin_amdgcn_mfma_f32_16x16x32_bf16(al[s2][rt].s8, bh, acc1[rt][cf], 0, 0, 0);
                    }
                }
            packW();                  // split next chunk (waits its loads)
        }
    }

    // ---------------- h1 = relu(acc1 + b1) -> packed h-image; stage W2 ------
    __syncthreads();                  // chunk19 B-reads done
    storeW();                         // W2 images
    loadWf(W3ne);                     // prefetch W3
    #pragma unroll
    for (int cf = 0; cf < 4; ++cf) {
        float bv = b1[(size_t)ne * H_ + cf * 16 + ccol];
        #pragma unroll
        for (int rt = 0; rt < 2; ++rt)
            #pragma unroll
            for (int reg = 0; reg < 4; ++reg) {
                float hv = fmaxf(acc1[rt][cf][reg] + bv, 0.f);
                unsigned u  = __float_as_uint(hv);
                unsigned ht = u & 0xffff0000u;
                float rem   = hv - __uint_as_float(ht);
                himg[(w * 32 + rt * 16 + qrow + reg) * HIMG_ROW + cf * 16 + ccol] =
                    ht | (__float_as_uint(rem) >> 16);      // wave-private rows
            }
    }
    packW();                          // split W3
    __syncthreads();                  // W2 images visible (+ own h1 rows)

    // ---------------- GEMM2: h1 @ W2 (K=64) ----------------
    float4v acc2[2][4];
    #pragma unroll
    for (int rt = 0; rt < 2; ++rt)
        #pragma unroll
        for (int cf = 0; cf < 4; ++cf) acc2[rt][cf] = (float4v)0.f;
    #pragma unroll
    for (int s2 = 0; s2 < 2; ++s2) {
        Frag ah[2], al[2];
        #pragma unroll
        for (int rt = 0; rt < 2; ++rt) {
            const unsigned* hp = himg + (w * 32 + rt * 16 + lrow) * HIMG_ROW + s2 * 32 + dseg;
            uint4 u0 = *(const uint4*)hp;
            uint4 u1 = *(const uint4*)(hp + 4);
            unsigned uu[8] = {u0.x, u0.y, u0.z, u0.w, u1.x, u1.y, u1.z, u1.w};
            #pragma unroll
            for (int i = 0; i < 4; ++i) {
                ah[rt].u[i] = (uu[2 * i] >> 16) | (uu[2 * i + 1] & 0xffff0000u);
                al[rt].u[i] = (uu[2 * i] & 0xffffu) | (uu[2 * i + 1] << 16);
            }
        }
        #pragma unroll
        for (int cf = 0; cf < 4; ++cf) {
            short8 bh = bfrag(s2, cf, 0);
            short8 bl = bfrag(s2, cf, 1);
            #pragma unroll
            for (int rt = 0; rt < 2; ++rt) {
                acc2[rt][cf] = __builtin_amdgcn_mfma_f32_16x16x32_bf16(ah[rt].s8, bh, acc2[rt][cf], 0, 0, 0);
                acc2[rt][cf] = __builtin_amdgcn_mfma_f32_16x16x32_bf16(ah[rt].s8, bl, acc2[rt][cf], 0, 0, 0);
                acc2[rt][cf] = __builtin_amdgcn_mfma_f32_16x16x32_bf16(al[rt].s8, bh, acc2[rt][cf], 0, 0, 0);
            }
        }
    }

    // ---------------- h2 = relu(acc2 + b2) -> h-image; stage W3 -------------
    __syncthreads();                  // W2 image + h1 reads done
    storeW();                         // W3 images
    #pragma unroll
    for (int cf = 0; cf < 4; ++cf) {
        float bv = b2[(size_t)ne * H_ + cf * 16 + ccol];
        #pragma unroll
        for (int rt = 0; rt < 2; ++rt)
            #pragma unroll
            for (int reg = 0; reg < 4; ++reg) {
                float hv = fmaxf(acc2[rt][cf][reg] + bv, 0.f);
                unsigned u  = __float_as_uint(hv);
                unsigned ht = u & 0xffff0000u;
                float rem   = hv - __uint_as_float(ht);
                himg[(w * 32 + rt * 16 + qrow + reg) * HIMG_ROW + cf * 16 + ccol] =
                    ht | (__float_as_uint(rem) >> 16);
            }
    }
    __syncthreads();                  // W3 images + h2 visible

    // ---------------- GEMM3: h2 @ W3 -> pred; err epilogue ------------------
    float4v acc3[2][4];
    #pragma unroll
    for (int rt = 0; rt < 2; ++rt)
        #pragma unroll
        for (int cf = 0; cf < 4; ++cf) acc3[rt][cf] = (float4v)0.f;
    #pragma unroll
    for (int s2 = 0; s2 < 2; ++s2) {
        Frag ah[2], al[2];
        #pragma unroll
        for (int rt = 0; rt < 2; ++rt) {
            const unsigned* hp = himg + (w * 32 + rt * 16 + lrow) * HIMG_ROW + s2 * 32 + dseg;
            uint4 u0 = *(const uint4*)hp;
            uint4 u1 = *(const uint4*)(hp + 4);
            unsigned uu[8] = {u0.x, u0.y, u0.z, u0.w, u1.x, u1.y, u1.z, u1.w};
            #pragma unroll
            for (int i = 0; i < 4; ++i) {
                ah[rt].u[i] = (uu[2 * i] >> 16) | (uu[2 * i + 1] & 0xffff0000u);
                al[rt].u[i] = (uu[2 * i] & 0xffffu) | (uu[2 * i + 1] << 16);
            }
        }
        #pragma unroll
        for (int cf = 0; cf < 4; ++cf) {
            short8 bh = bfrag(s2, cf, 0);
            short8 bl = bfrag(s2, cf, 1);
            #pragma unroll
            for (int rt = 0; rt < 2; ++rt) {
                acc3[rt][cf] = __builtin_amdgcn_mfma_f32_16x16x32_bf16(ah[rt].s8, bh, acc3[rt][cf], 0, 0, 0);
                acc3[rt][cf] = __builtin_amdgcn_mfma_f32_16x16x32_bf16(ah[rt].s8, bl, acc3[rt][cf], 0, 0, 0);
                acc3[rt][cf] = __builtin_amdgcn_mfma_f32_16x16x32_bf16(al[rt].s8, bh, acc3[rt][cf], 0, 0, 0);
            }
        }
    }

    {
        float b3v[4];
        #pragma unroll
        for (int cf = 0; cf < 4; ++cf) b3v[cf] = b3[(size_t)ne * D_ + cf * 16 + ccol];

        #pragma unroll
        for (int rt = 0; rt < 2; ++rt) {
            #pragma unroll
            for (int reg = 0; reg < 4; ++reg) {
                const int m  = rowbase + rt * 16 + qrow + reg;
                const int mc = m < M_ ? m : M_ - 1;
                const int b = mc / TW, t = mc % TW;
                const float* yp = x + ((size_t)(b * T_ + t + 2) * N_ + n) * D_;
                float s = 0.f;
                #pragma unroll
                for (int cf = 0; cf < 4; ++cf) {
                    float d = acc3[rt][cf][reg] + b3v[cf] - yp[cf * 16 + ccol];
                    s += d * d;
                }
                s += __shfl_xor(s, 1);
                s += __shfl_xor(s, 2);
                s += __shfl_xor(s, 4);
                s += __shfl_xor(s, 8);
                if (ccol == 0 && m < M_) {
                    err_ws[((size_t)m * N_ + n) * E_ + e] = s * (1.f / 64.f);
                }
            }
        }
    }
}

// ---------------------------------------------------------------------------
// Reduce: per (m,n) min/argmin over E, softmax(-err) KL; block atomicAdd.
__global__ __launch_bounds__(256) void moe_reduce_kernel(
    const float* __restrict__ err_ws, float* __restrict__ out)
{
    const int tid = threadIdx.x;
    const int idx = blockIdx.x * 256 + tid;
    float v = 0.f;
    if (idx < M_ * N_) {
        const int m = idx / N_, n = idx % N_;
        const float* ep = err_ws + (size_t)idx * E_;
        float ev[E_];
        float mn = ep[0];
        int am = 0;
        ev[0] = mn;
        #pragma unroll
        for (int i = 1; i < E_; ++i) {
            ev[i] = ep[i];
            if (ev[i] < mn) { mn = ev[i]; am = i; }
        }
        float p[E_];
        float Z = 0.f;
        #pragma unroll
        for (int i = 0; i < E_; ++i) { p[i] = expf(mn - ev[i]); Z += p[i]; }
        const float invZ = 1.f / Z;
        float kl = 0.f;
        #pragma unroll
        for (int i = 0; i < E_; ++i) {
            float q = p[i] * invZ;
            kl += q * (logf(q + 1e-9f) + 2.0794415416798357f);  // log(8)
        }
        v = mn + 0.01f * kl;
        const int t = m % TW, b = m / TW;
        if (t == TW - 1 && n == N_ - 1) out[1 + b] = (float)am;
    }
    __shared__ float sd[256];
    sd[tid] = v;
    __syncthreads();
    for (int s = 128; s > 0; s >>= 1) {
        if (tid < s) sd[tid] += sd[tid + s];
        __syncthreads();
    }
    if (tid == 0) atomicAdd(out, sd[0] * (1.f / 20160.f));  // / B / (N-1) / (T-4)
}

__global__ void init_out_kernel(float* out)
{
    if (threadIdx.x == 0) out[0] = 0.f;
}

extern "C" void kernel_launch(void* const* d_in, const int* in_sizes, int n_in,
                              void* d_out, int out_size, void* d_ws, size_t ws_size,
                              hipStream_t stream)
{
    const float* x  = (const float*)d_in[0];
    const int*   nb = (const int*)d_in[1];
    const float* W1 = (const float*)d_in[2];
    const float* b1 = (const float*)d_in[3];
    const float* W2 = (const float*)d_in[4];
    const float* b2 = (const float*)d_in[5];
    const float* W3 = (const float*)d_in[6];
    const float* b3 = (const float*)d_in[7];
    float* out    = (float*)d_out;
    float* err_ws = (float*)d_ws;
    short* xh     = (short*)((char*)d_ws + XH_OFF);
    short* xl     = (short*)((char*)d_ws + XL_OFF);

    hipLaunchKernelGGL(init_out_kernel, dim3(1), dim3(64), 0, stream, out);
    hipLaunchKernelGGL(xsplit_kernel, dim3(1408), dim3(256), 0, stream, x, xh, xl);
    hipLaunchKernelGGL(moe_err_kernel, dim3(NE_ * 8), dim3(256), 0, stream,
                       x, xh, xl, nb, W1, W2, W3, b1, b2, b3, err_ws);
    const int nred = (M_ * N_ + 255) / 256;
    hipLaunchKernelGGL(moe_reduce_kernel, dim3(nred), dim3(256), 0, stream, err_ws, out);
}